// Round 19
// baseline (285.039 us; speedup 1.0000x reference)
//
#include <hip/hip_runtime.h>
#include <hip/hip_bf16.h>

// Transformer block fwd (B=2,T=2048,C=1024,H=16,D=64,HID=4096), bf16 MFMA compute.
// Round 19: R18 + MLP2 split-K 2->4 (1024 blocks, 4/CU; atomic f32 onto seeded out).
//           GEMMs: 128^2 dbuf+counted-vmcnt+swizzle. Attn: KV-split x2 + merge.

#define B_ 2
#define T_ 2048
#define C_ 1024
#define H_ 16
#define D_ 64
#define HID_ 4096
#define M_ 4096  // B*T
#define NQKV 3072

typedef __bf16 bf16x8 __attribute__((ext_vector_type(8)));
typedef float f32x4 __attribute__((ext_vector_type(4)));
using bf16 = __hip_bfloat16;

#define WAIT_VM(N) asm volatile("s_waitcnt vmcnt(" #N ")" ::: "memory")
#define SBAR() asm volatile("s_barrier" ::: "memory")

static __device__ __forceinline__ f32x4 mfma16(bf16x8 a, bf16x8 b, f32x4 c) {
  return __builtin_amdgcn_mfma_f32_16x16x32_bf16(a, b, c, 0, 0, 0);
}

static __device__ __forceinline__ void gload16(const bf16* g, bf16* l) {
  __builtin_amdgcn_global_load_lds(
      (const __attribute__((address_space(1))) unsigned int*)g,
      (__attribute__((address_space(3))) unsigned int*)l, 16, 0, 0);
}

static __device__ __forceinline__ unsigned short bfbits(float x) {
  __hip_bfloat16 h = __float2bfloat16(x);
  return *(unsigned short*)&h;
}

// overflow-safe tanh-form GELU (|err| vs erf-GELU ~3e-3 << 0.119 tolerance)
static __device__ __forceinline__ float gelu_tanh(float v) {
  float z = 0.7978845608f * (v + 0.044715f * v * v * v);
  float az = fabsf(z);
  float e = __expf(-2.0f * az);
  float th = (1.0f - e) / (1.0f + e);
  th = copysignf(th, z);
  return 0.5f * v * (1.0f + th);
}

// ---- prep_all: one dispatch: 6 weight transposes (f32 [K][N] -> bf16 [N][K]) + bias pack.
__global__ __launch_bounds__(256) void prep_all(
    const float* __restrict__ q_w, const float* __restrict__ k_w,
    const float* __restrict__ v_w, const float* __restrict__ o_w,
    const float* __restrict__ w1, const float* __restrict__ w2,
    const float* __restrict__ q_b, const float* __restrict__ k_b,
    const float* __restrict__ v_b, bf16* __restrict__ qkvT, bf16* __restrict__ owT,
    bf16* __restrict__ w1T, bf16* __restrict__ w2T, float* __restrict__ qkvb) {
  int bid = blockIdx.x, tid = threadIdx.x;
  if (bid >= 12288) {
    int i = (bid - 12288) * 256 + tid;
    qkvb[i] = i < 1024 ? q_b[i] : (i < 2048 ? k_b[i - 1024] : v_b[i - 2048]);
    return;
  }
  const float* in;
  bf16* out;
  int K, N, tile;
  if (bid < 4096) {
    int which = bid >> 10;
    tile = bid & 1023;
    K = 1024; N = 1024;
    if (which == 0) { in = q_w; out = qkvT; }
    else if (which == 1) { in = k_w; out = qkvT + 1048576; }
    else if (which == 2) { in = v_w; out = qkvT + 2097152; }
    else { in = o_w; out = owT; }
  } else if (bid < 8192) {
    tile = bid - 4096; K = 1024; N = 4096; in = w1; out = w1T;
  } else {
    tile = bid - 8192; K = 4096; N = 1024; in = w2; out = w2T;
  }
  int ntx = N >> 5;
  int n0 = (tile % ntx) * 32, k0 = (tile / ntx) * 32;
  __shared__ float t32[32][33];
  int tx = tid & 31, ty = tid >> 5;
#pragma unroll
  for (int i = 0; i < 4; ++i) {
    int r = ty + i * 8;
    t32[r][tx] = in[(size_t)(k0 + r) * N + n0 + tx];
  }
  __syncthreads();
#pragma unroll
  for (int i = 0; i < 4; ++i) {
    int r = ty + i * 8;
    out[(size_t)(n0 + r) * K + k0 + tx] = __float2bfloat16(t32[tx][r]);
  }
}

// ---- RMSNorm: x f32 [rows][1024] -> out bf16 ----
__global__ __launch_bounds__(256) void rmsnorm_kernel(const float* __restrict__ x,
                                                      const float* __restrict__ w,
                                                      bf16* __restrict__ out) {
  int row = blockIdx.x, tid = threadIdx.x;
  float4 v = ((const float4*)(x + (size_t)row * C_))[tid];
  float ss = v.x * v.x + v.y * v.y + v.z * v.z + v.w * v.w;
#pragma unroll
  for (int d = 1; d < 64; d <<= 1) ss += __shfl_xor(ss, d);
  __shared__ float wsum[4];
  if ((tid & 63) == 0) wsum[tid >> 6] = ss;
  __syncthreads();
  float tot = wsum[0] + wsum[1] + wsum[2] + wsum[3];
  float r = rsqrtf(tot * (1.0f / C_) + 1e-5f);
  float4 wv = ((const float4*)w)[tid];
  bf16* o = out + (size_t)row * C_ + tid * 4;
  o[0] = __float2bfloat16(v.x * wv.x * r);
  o[1] = __float2bfloat16(v.y * wv.y * r);
  o[2] = __float2bfloat16(v.z * wv.z * r);
  o[3] = __float2bfloat16(v.w * wv.w * r);
}

// ---- qkv_post: from C[4096][3072] bf16 produce kout/vout f32 (B,H,T,D) and
// vtb bf16 V^T (B,H,D,T). All reads/writes coalesced; V^T via LDS tile (ushort bits).
__global__ __launch_bounds__(256) void qkv_post(const bf16* __restrict__ Cq,
                                                bf16* __restrict__ vtb,
                                                float* __restrict__ kout,
                                                float* __restrict__ vout) {
  __shared__ unsigned short vt[64][33];
  int tid = threadIdx.x, bh = blockIdx.y, t0 = blockIdx.x * 32;
  int b = bh >> 4, hh = bh & 15;
  int row = tid >> 3, db8 = (tid & 7) * 8;
  const bf16* Ck = Cq + (size_t)(b * 2048 + t0) * NQKV + 1024 + hh * 64;
  bf16x8 kv = *(const bf16x8*)&Ck[(size_t)row * NQKV + db8];
  float* kd = kout + ((size_t)bh * 2048 + t0 + row) * 64 + db8;
#pragma unroll
  for (int j = 0; j < 8; ++j) kd[j] = (float)kv[j];
  bf16x8 vv = *(const bf16x8*)&Ck[(size_t)row * NQKV + 1024 + db8];
  const unsigned short* vb = (const unsigned short*)&vv;
  float* vd = vout + ((size_t)bh * 2048 + t0 + row) * 64 + db8;
#pragma unroll
  for (int j = 0; j < 8; ++j) {
    vd[j] = (float)vv[j];
    vt[db8 + j][row] = vb[j];
  }
  __syncthreads();
  int d = tid >> 2, t8 = (tid & 3) * 8;
  union { unsigned short u[8]; bf16x8 v8; } o;
#pragma unroll
  for (int j = 0; j < 8; ++j) o.u[j] = vt[d][t8 + j];
  *(bf16x8*)&vtb[((size_t)bh * 64 + d) * 2048 + t0 + t8] = o.v8;
}

// ---- 128^2 GEMM: dbuf + counted-vmcnt + granule-XOR LDS swizzle, 4 waves, BK=64.
// EPI 5: plain bf16 row-major = acc+bias (QKV).  EPI 2: bf16 = gelu_tanh(acc+bias).
// EPI 3: x2 = acc+bias+res AND seed paux = x2 + bias2 (o-proj).
// EPI 4: atomicAdd(fout, acc) — split-K partials onto seeded output.
template <int EPI, int SK>
__global__ __launch_bounds__(256) void gemm_kernel(
    const bf16* __restrict__ A, const bf16* __restrict__ Bt, const float* __restrict__ bias,
    bf16* __restrict__ bfout, float* __restrict__ fout, const float* __restrict__ res,
    float* __restrict__ paux, const float* __restrict__ bias2, int M, int N, int K) {
  __shared__ bf16 Al[2 * 128 * 64];
  __shared__ bf16 Bl[2 * 128 * 64];
  int tid = threadIdx.x, w = tid >> 6, l = tid & 63;
  int g = l >> 4, c = l & 15;
  int nwg = gridDim.x * gridDim.y;
  int bidl = blockIdx.y * gridDim.x + blockIdx.x;
  int wgid = (bidl & 7) * (nwg >> 3) + (bidl >> 3);
  int bx = wgid % gridDim.x, by = wgid / gridDim.x;
  int m0 = by * 128, n0 = bx * 128;
  int wm = (w >> 1) * 64, wn = (w & 1) * 64;
  int Kc = K / SK;
  int kbase = (SK > 1) ? (int)blockIdx.z * Kc : 0;
  int KT = Kc >> 6;
  int lrow = l >> 3;
  int sgr = (l & 7) ^ lrow;  // pre-swizzled source granule (involution w/ read)

  const bf16* gA = A + (size_t)(m0 + w * 32 + lrow) * K + kbase + sgr * 8;
  const bf16* gB = Bt + (size_t)(n0 + w * 32 + lrow) * K + kbase + sgr * 8;

  auto stage = [&](int kt, int buf) {
#pragma unroll
    for (int i = 0; i < 4; ++i) {
      gload16(gA + (size_t)i * 8 * K + kt * 64, Al + buf * 8192 + (w * 4 + i) * 512);
      gload16(gB + (size_t)i * 8 * K + kt * 64, Bl + buf * 8192 + (w * 4 + i) * 512);
    }
  };
  auto compute = [&](int buf, f32x4 (&acc)[4][4]) {
#pragma unroll
    for (int ch = 0; ch < 2; ++ch) {
      bf16x8 af[4], bfr[4];
#pragma unroll
      for (int f = 0; f < 4; ++f)
        af[f] = *(const bf16x8*)&Al[buf * 8192 + (wm + f * 16 + c) * 64 +
                                    (((ch * 4 + g) ^ (c & 7)) << 3)];
#pragma unroll
      for (int f = 0; f < 4; ++f)
        bfr[f] = *(const bf16x8*)&Bl[buf * 8192 + (wn + f * 16 + c) * 64 +
                                     (((ch * 4 + g) ^ (c & 7)) << 3)];
#pragma unroll
      for (int mf = 0; mf < 4; ++mf)
#pragma unroll
        for (int nf = 0; nf < 4; ++nf) acc[mf][nf] = mfma16(af[mf], bfr[nf], acc[mf][nf]);
    }
  };

  f32x4 acc[4][4] = {};
  stage(0, 0);
  for (int kt = 0; kt < KT; ++kt) {
    int cur = kt & 1;
    if (kt + 1 < KT) {
      stage(kt + 1, cur ^ 1);
      WAIT_VM(8);  // own tile-kt loads landed; next tile's 8 stay in flight
    } else {
      WAIT_VM(0);
    }
    SBAR();
    __builtin_amdgcn_s_setprio(1);
    compute(cur, acc);
    __builtin_amdgcn_s_setprio(0);
    __builtin_amdgcn_sched_barrier(0);
    SBAR();
  }

#pragma unroll
  for (int mf = 0; mf < 4; ++mf) {
#pragma unroll
    for (int nf = 0; nf < 4; ++nf) {
      int gn = n0 + wn + nf * 16 + c;
      float bv = bias ? bias[gn] : 0.f;
#pragma unroll
      for (int r = 0; r < 4; ++r) {
        int gm = m0 + wm + mf * 16 + g * 4 + r;
        float vr = acc[mf][nf][r];
        float v = vr + bv;
        if (EPI == 4) {
          atomicAdd(fout + (size_t)gm * N + gn, vr);
        } else if (EPI == 5) {
          bfout[(size_t)gm * N + gn] = __float2bfloat16(v);
        } else if (EPI == 3) {
          size_t idx = (size_t)gm * N + gn;
          float t = v + res[idx];
          fout[idx] = t;                 // x2
          paux[idx] = t + bias2[gn];     // seed out for MLP2 atomics
        } else {  // EPI == 2
          size_t idx = (size_t)gm * N + gn;
          bfout[idx] = __float2bfloat16(gelu_tanh(v));
        }
      }
    }
  }
}

// ---- Flash attention (causal), KV-split x2, Q/K read from C[4096][3072] (strided),
// V^T from vtb. Swapped QK^T; unnormalized o + m,l partials. Mask -3e38.
__global__ __launch_bounds__(256, 2) void attn_kernel(const bf16* __restrict__ Cq,
                                                      const bf16* __restrict__ Vt,
                                                      bf16* __restrict__ o0p,
                                                      bf16* __restrict__ o1p,
                                                      float* __restrict__ ml) {
  constexpr int LDP = 72;
  __shared__ bf16 Kl[2][64 * 64];
  __shared__ bf16 Vl[2][64 * 64];
  __shared__ bf16 Pl[4][2][16 * LDP];
  __shared__ float alw[4][2][16];
  int tid = threadIdx.x, w = tid >> 6, l = tid & 63, g = l >> 4, c = l & 15;
  int bid = blockIdx.x;
  int bh = bid & 31;
  int rest = bid >> 5;
  int qt = 15 - (rest >> 1);
  int half = rest & 1;
  int qbase = qt * 128 + w * 32;
  int b = bh >> 4, hh = bh & 15;
  const bf16* Qh = Cq + (size_t)(b * 2048) * NQKV + hh * 64;  // [t][d] stride NQKV
  const bf16* Kh = Qh + 1024;
  const bf16* Vh = Vt + (size_t)bh * T_ * D_;                 // [d][t]

  int NT = 2 * qt + 2, H0 = qt + 1;
  int t0 = half ? H0 : 0, t1 = half ? NT : H0;

  int srow = l >> 3;
  int sce = ((l & 7) * 8) ^ (srow << 3);
  int cswz = (c & 7) << 3;

  auto stage = [&](int ti, int buf) {
#pragma unroll
    for (int i = 0; i < 2; ++i) {
      int row = i * 32 + w * 8 + srow;
      gload16(&Kh[(size_t)(ti * 64 + row) * NQKV + sce], &Kl[buf][i * 2048 + w * 512]);
      gload16(&Vh[(size_t)row * T_ + ti * 64 + sce], &Vl[buf][i * 2048 + w * 512]);
    }
  };

  stage(t0, 0);

  bf16x8 aq[2][2];
#pragma unroll
  for (int qf = 0; qf < 2; ++qf)
#pragma unroll
    for (int ch = 0; ch < 2; ++ch)
      aq[qf][ch] =
          *(const bf16x8*)&Qh[(size_t)(qbase + qf * 16 + c) * NQKV + ch * 32 + g * 8];

  f32x4 o[2][4] = {};
  float mrun[2] = {-1e30f, -1e30f};
  float lrun[2] = {0.f, 0.f};

  __syncthreads();

  for (int ti = t0; ti < t1; ++ti) {
    int cur = (ti - t0) & 1;
    int kv0 = ti * 64;
    if (ti + 1 < t1) stage(ti + 1, cur ^ 1);

    f32x4 sf[2][4];
#pragma unroll
    for (int kb = 0; kb < 4; ++kb) {
      bf16x8 bk0 = *(const bf16x8*)&Kl[cur][(kb * 16 + c) * 64 + ((g * 8) ^ cswz)];
      bf16x8 bk1 = *(const bf16x8*)&Kl[cur][(kb * 16 + c) * 64 + ((32 + g * 8) ^ cswz)];
#pragma unroll
      for (int qf = 0; qf < 2; ++qf) {
        f32x4 t = {};
        t = mfma16(bk0, aq[qf][0], t);
        t = mfma16(bk1, aq[qf][1], t);
        sf[qf][kb] = t;
      }
    }

    float s[2][4][4];
#pragma unroll
    for (int qf = 0; qf < 2; ++qf)
#pragma unroll
      for (int kb = 0; kb < 4; ++kb)
#pragma unroll
        for (int r = 0; r < 4; ++r) s[qf][kb][r] = sf[qf][kb][r] * 0.125f;
    if (kv0 + 63 > qbase) {
#pragma unroll
      for (int qf = 0; qf < 2; ++qf)
#pragma unroll
        for (int kb = 0; kb < 4; ++kb)
#pragma unroll
          for (int r = 0; r < 4; ++r) {
            int qi = qbase + qf * 16 + c;
            int kv = kv0 + kb * 16 + g * 4 + r;
            if (kv > qi) s[qf][kb][r] = -3.0e38f;
          }
    }

#pragma unroll
    for (int qf = 0; qf < 2; ++qf) {
      float m01 = fmaxf(fmaxf(s[qf][0][0], s[qf][0][1]), fmaxf(s[qf][0][2], s[qf][0][3]));
      float m23 = fmaxf(fmaxf(s[qf][1][0], s[qf][1][1]), fmaxf(s[qf][1][2], s[qf][1][3]));
      float m45 = fmaxf(fmaxf(s[qf][2][0], s[qf][2][1]), fmaxf(s[qf][2][2], s[qf][2][3]));
      float m67 = fmaxf(fmaxf(s[qf][3][0], s[qf][3][1]), fmaxf(s[qf][3][2], s[qf][3][3]));
      float tm = fmaxf(fmaxf(m01, m23), fmaxf(m45, m67));
      tm = fmaxf(tm, __shfl_xor(tm, 16));
      tm = fmaxf(tm, __shfl_xor(tm, 32));
      float mn = fmaxf(mrun[qf], tm);
      float al = __expf(mrun[qf] - mn);
      mrun[qf] = mn;
      float asum = 0.f;
#pragma unroll
      for (int kb = 0; kb < 4; ++kb)
#pragma unroll
        for (int r = 0; r < 4; ++r) {
          float pv = __expf(s[qf][kb][r] - mn);
          s[qf][kb][r] = pv;
          asum += pv;
        }
      asum += __shfl_xor(asum, 16);
      asum += __shfl_xor(asum, 32);
      lrun[qf] = lrun[qf] * al + asum;
      if (l < 16) alw[w][qf][c] = al;
    }

#pragma unroll
    for (int qf = 0; qf < 2; ++qf)
#pragma unroll
      for (int kb = 0; kb < 4; ++kb) {
        union { unsigned short u[4]; uint2 v2; } pk;
#pragma unroll
        for (int r = 0; r < 4; ++r) pk.u[r] = bfbits(s[qf][kb][r]);
        *(uint2*)&Pl[w][qf][c * LDP + kb * 16 + g * 4] = pk.v2;
      }

#pragma unroll
    for (int qf = 0; qf < 2; ++qf) {
      f32x4 a4 = *(const f32x4*)&alw[w][qf][g * 4];
#pragma unroll
      for (int db = 0; db < 4; ++db)
#pragma unroll
        for (int r = 0; r < 4; ++r) o[qf][db][r] *= a4[r];
    }

    bf16x8 bvv[4][2];
#pragma unroll
    for (int db = 0; db < 4; ++db)
#pragma unroll
      for (int ck = 0; ck < 2; ++ck)
        bvv[db][ck] = *(const bf16x8*)&Vl[cur][(db * 16 + c) * 64 + ((ck * 32 + g * 8) ^ cswz)];

#pragma unroll
    for (int qf = 0; qf < 2; ++qf) {
      bf16x8 pa0 = *(const bf16x8*)&Pl[w][qf][c * LDP + g * 8];
      bf16x8 pa1 = *(const bf16x8*)&Pl[w][qf][c * LDP + 32 + g * 8];
#pragma unroll
      for (int db = 0; db < 4; ++db) {
        o[qf][db] = mfma16(pa0, bvv[db][0], o[qf][db]);
        o[qf][db] = mfma16(pa1, bvv[db][1], o[qf][db]);
      }
    }
    __syncthreads();
  }

  bf16* op = half ? o1p : o0p;
  int rowbase = bh * 2048 + qt * 128 + w * 32;
#pragma unroll
  for (int qf = 0; qf < 2; ++qf)
#pragma unroll
    for (int r = 0; r < 4; ++r)
#pragma unroll
      for (int db = 0; db < 4; ++db)
        op[(size_t)(rowbase + qf * 16 + g * 4 + r) * 64 + db * 16 + c] =
            __float2bfloat16(o[qf][db][r]);
  if (l < 16) {
    float* mh = ml + half * 131072;
#pragma unroll
    for (int qf = 0; qf < 2; ++qf) {
      mh[rowbase + qf * 16 + c] = mrun[qf];
      mh[65536 + rowbase + qf * 16 + c] = lrun[qf];
    }
  }
}

// ---- merge the two KV-halves ----
__global__ __launch_bounds__(256) void merge_attn(const bf16* __restrict__ o0,
                                                  const bf16* __restrict__ o1,
                                                  const float* __restrict__ ml,
                                                  bf16* __restrict__ ctx) {
  int idx = blockIdx.x * 256 + threadIdx.x;
  int row = idx >> 2, dc = (idx & 3) * 16;
  float m0 = ml[row], l0 = ml[65536 + row];
  float m1 = ml[131072 + row], l1 = ml[196608 + row];
  float Mx = fmaxf(m0, m1);
  float s0 = __expf(m0 - Mx), s1 = __expf(m1 - Mx);
  float inv = 1.0f / (l0 * s0 + l1 * s1);
  const bf16x8* p0 = (const bf16x8*)&o0[(size_t)row * 64 + dc];
  const bf16x8* p1 = (const bf16x8*)&o1[(size_t)row * 64 + dc];
  bf16x8 a0 = p0[0], a1 = p0[1], b0 = p1[0], b1 = p1[1];
  int bh = row >> 11, t = row & 2047;
  int b_ = bh >> 4, hh = bh & 15;
  bf16* dst = ctx + ((size_t)(b_ * T_ + t)) * C_ + hh * D_ + dc;
#pragma unroll
  for (int j = 0; j < 8; ++j) {
    dst[j] = __float2bfloat16(((float)a0[j] * s0 + (float)b0[j] * s1) * inv);
    dst[8 + j] = __float2bfloat16(((float)a1[j] * s0 + (float)b1[j] * s1) * inv);
  }
}

extern "C" void kernel_launch(void* const* d_in, const int* in_sizes, int n_in, void* d_out,
                              int out_size, void* d_ws, size_t ws_size, hipStream_t stream) {
  const float* x = (const float*)d_in[0];
  const float* anw = (const float*)d_in[2];
  const float* mnw = (const float*)d_in[3];
  const float* q_w = (const float*)d_in[4];
  const float* q_b = (const float*)d_in[5];
  const float* k_w = (const float*)d_in[6];
  const float* k_b = (const float*)d_in[7];
  const float* v_w = (const float*)d_in[8];
  const float* v_b = (const float*)d_in[9];
  const float* o_w = (const float*)d_in[10];
  const float* o_b = (const float*)d_in[11];
  const float* w1 = (const float*)d_in[12];
  const float* b1 = (const float*)d_in[13];
  const float* w2 = (const float*)d_in[14];
  const float* b2 = (const float*)d_in[15];
  float* out = (float*)d_out;
  char* ws = (char*)d_ws;

  // ws map (80 MB), MB offsets:
  bf16* owT = (bf16*)(ws + 0);                    // 0-2
  bf16* w1T = (bf16*)(ws + 2097152);              // 2-10
  bf16* w2T = (bf16*)(ws + 10485760);             // 10-18
  bf16* h = (bf16*)(ws + 18874368);               // 18-26 (also m)
  bf16* qkvT = (bf16*)(ws + 27262976);            // 26-32; dead after QKV
  bf16* Cq = (bf16*)(ws + 33554432);              // 32-56 [4096][3072]; dead after attn
  bf16* vtb = (bf16*)(ws + 58720256);             // 56-64; dead after attn
  bf16* o0p = (bf16*)(ws + 67108864);             // 64-72; dead after merge
  bf16* o1p = (bf16*)(ws + 75497472);             // 72-80; dead after merge
  float* ml = (float*)(ws + 27262976);            // 26-27 over qkvT (dead after QKV)
  float* qkvb = (float*)(ws + 67108864);          // over o0p (dead before attn)
  bf16* ctx = (bf16*)(ws + 33554432);             // 32-40 over Cq head (after attn)
  float* x2 = (float*)(ws + 41943040);            // 40-56 over Cq tail
  bf16* m = h;
  bf16* hid = (bf16*)(ws + 50331648);             // 48-80 (x2 dead after rms2)

  // one dispatch: all weight transposes + bias pack
  prep_all<<<12300, 256, 0, stream>>>(q_w, k_w, v_w, o_w, w1, w2, q_b, k_b, v_b,
                                      qkvT, owT, w1T, w2T, qkvb);

  rmsnorm_kernel<<<4096, 256, 0, stream>>>(x, anw, h);

  // fused QKV -> plain row-major bf16 C[4096][3072]
  gemm_kernel<5, 1><<<dim3(24, 32), 256, 0, stream>>>(
      h, qkvT, qkvb, Cq, nullptr, nullptr, nullptr, nullptr, 4096, 3072, 1024);

  // k/v f32 outputs + V^T (all coalesced)
  qkv_post<<<dim3(64, 32), 256, 0, stream>>>(Cq, vtb, out + 4194304, out + 8388608);

  // attention, KV-split x2 + merge
  attn_kernel<<<1024, 256, 0, stream>>>(Cq, vtb, o0p, o1p, ml);
  merge_attn<<<1024, 256, 0, stream>>>(o0p, o1p, ml, ctx);

  // o-proj: x2 = ctx@o_w + o_b + x; seed out = x2 + b2
  gemm_kernel<3, 1><<<dim3(8, 32), 256, 0, stream>>>(
      ctx, owT, o_b, nullptr, x2, x, out, b2, 4096, 1024, 1024);

  rmsnorm_kernel<<<4096, 256, 0, stream>>>(x2, mnw, m);

  // MLP1 (tanh gelu)
  gemm_kernel<2, 1><<<dim3(32, 32), 256, 0, stream>>>(
      m, w1T, b1, hid, nullptr, nullptr, nullptr, nullptr, 4096, 4096, 1024);
  // MLP2 split-K=4 (1024 blocks, 4/CU), atomic onto seeded out
  gemm_kernel<4, 4><<<dim3(8, 32, 4), 256, 0, stream>>>(
      hid, w2T, nullptr, nullptr, out, nullptr, nullptr, nullptr, 4096, 1024, 4096);
}

// Round 20
// 262.265 us; speedup vs baseline: 1.0868x; 1.0868x over previous
//
#include <hip/hip_runtime.h>
#include <hip/hip_bf16.h>

// Transformer block fwd (B=2,T=2048,C=1024,H=16,D=64,HID=4096), bf16 MFMA compute.
// FINAL (= R18, measured best 262.6us): fused prep dispatch; 128^2 GEMMs with
// dbuf + counted-vmcnt + granule-XOR swizzle; QKV -> row-major C + qkv_post;
// KV-split x2 flash attention + merge; tanh GELU; MLP2 atomic split-K=2.

#define B_ 2
#define T_ 2048
#define C_ 1024
#define H_ 16
#define D_ 64
#define HID_ 4096
#define M_ 4096  // B*T
#define NQKV 3072

typedef __bf16 bf16x8 __attribute__((ext_vector_type(8)));
typedef float f32x4 __attribute__((ext_vector_type(4)));
using bf16 = __hip_bfloat16;

#define WAIT_VM(N) asm volatile("s_waitcnt vmcnt(" #N ")" ::: "memory")
#define SBAR() asm volatile("s_barrier" ::: "memory")

static __device__ __forceinline__ f32x4 mfma16(bf16x8 a, bf16x8 b, f32x4 c) {
  return __builtin_amdgcn_mfma_f32_16x16x32_bf16(a, b, c, 0, 0, 0);
}

static __device__ __forceinline__ void gload16(const bf16* g, bf16* l) {
  __builtin_amdgcn_global_load_lds(
      (const __attribute__((address_space(1))) unsigned int*)g,
      (__attribute__((address_space(3))) unsigned int*)l, 16, 0, 0);
}

static __device__ __forceinline__ unsigned short bfbits(float x) {
  __hip_bfloat16 h = __float2bfloat16(x);
  return *(unsigned short*)&h;
}

// overflow-safe tanh-form GELU (|err| vs erf-GELU ~3e-3 << 0.119 tolerance)
static __device__ __forceinline__ float gelu_tanh(float v) {
  float z = 0.7978845608f * (v + 0.044715f * v * v * v);
  float az = fabsf(z);
  float e = __expf(-2.0f * az);
  float th = (1.0f - e) / (1.0f + e);
  th = copysignf(th, z);
  return 0.5f * v * (1.0f + th);
}

// ---- prep_all: one dispatch: 6 weight transposes (f32 [K][N] -> bf16 [N][K]) + bias pack.
__global__ __launch_bounds__(256) void prep_all(
    const float* __restrict__ q_w, const float* __restrict__ k_w,
    const float* __restrict__ v_w, const float* __restrict__ o_w,
    const float* __restrict__ w1, const float* __restrict__ w2,
    const float* __restrict__ q_b, const float* __restrict__ k_b,
    const float* __restrict__ v_b, bf16* __restrict__ qkvT, bf16* __restrict__ owT,
    bf16* __restrict__ w1T, bf16* __restrict__ w2T, float* __restrict__ qkvb) {
  int bid = blockIdx.x, tid = threadIdx.x;
  if (bid >= 12288) {
    int i = (bid - 12288) * 256 + tid;
    qkvb[i] = i < 1024 ? q_b[i] : (i < 2048 ? k_b[i - 1024] : v_b[i - 2048]);
    return;
  }
  const float* in;
  bf16* out;
  int K, N, tile;
  if (bid < 4096) {
    int which = bid >> 10;
    tile = bid & 1023;
    K = 1024; N = 1024;
    if (which == 0) { in = q_w; out = qkvT; }
    else if (which == 1) { in = k_w; out = qkvT + 1048576; }
    else if (which == 2) { in = v_w; out = qkvT + 2097152; }
    else { in = o_w; out = owT; }
  } else if (bid < 8192) {
    tile = bid - 4096; K = 1024; N = 4096; in = w1; out = w1T;
  } else {
    tile = bid - 8192; K = 4096; N = 1024; in = w2; out = w2T;
  }
  int ntx = N >> 5;
  int n0 = (tile % ntx) * 32, k0 = (tile / ntx) * 32;
  __shared__ float t32[32][33];
  int tx = tid & 31, ty = tid >> 5;
#pragma unroll
  for (int i = 0; i < 4; ++i) {
    int r = ty + i * 8;
    t32[r][tx] = in[(size_t)(k0 + r) * N + n0 + tx];
  }
  __syncthreads();
#pragma unroll
  for (int i = 0; i < 4; ++i) {
    int r = ty + i * 8;
    out[(size_t)(n0 + r) * K + k0 + tx] = __float2bfloat16(t32[tx][r]);
  }
}

// ---- RMSNorm: x f32 [rows][1024] -> out bf16 ----
__global__ __launch_bounds__(256) void rmsnorm_kernel(const float* __restrict__ x,
                                                      const float* __restrict__ w,
                                                      bf16* __restrict__ out) {
  int row = blockIdx.x, tid = threadIdx.x;
  float4 v = ((const float4*)(x + (size_t)row * C_))[tid];
  float ss = v.x * v.x + v.y * v.y + v.z * v.z + v.w * v.w;
#pragma unroll
  for (int d = 1; d < 64; d <<= 1) ss += __shfl_xor(ss, d);
  __shared__ float wsum[4];
  if ((tid & 63) == 0) wsum[tid >> 6] = ss;
  __syncthreads();
  float tot = wsum[0] + wsum[1] + wsum[2] + wsum[3];
  float r = rsqrtf(tot * (1.0f / C_) + 1e-5f);
  float4 wv = ((const float4*)w)[tid];
  bf16* o = out + (size_t)row * C_ + tid * 4;
  o[0] = __float2bfloat16(v.x * wv.x * r);
  o[1] = __float2bfloat16(v.y * wv.y * r);
  o[2] = __float2bfloat16(v.z * wv.z * r);
  o[3] = __float2bfloat16(v.w * wv.w * r);
}

// ---- qkv_post: from C[4096][3072] bf16 produce kout/vout f32 (B,H,T,D) and
// vtb bf16 V^T (B,H,D,T). All reads/writes coalesced; V^T via LDS tile (ushort bits).
__global__ __launch_bounds__(256) void qkv_post(const bf16* __restrict__ Cq,
                                                bf16* __restrict__ vtb,
                                                float* __restrict__ kout,
                                                float* __restrict__ vout) {
  __shared__ unsigned short vt[64][33];
  int tid = threadIdx.x, bh = blockIdx.y, t0 = blockIdx.x * 32;
  int b = bh >> 4, hh = bh & 15;
  int row = tid >> 3, db8 = (tid & 7) * 8;
  const bf16* Ck = Cq + (size_t)(b * 2048 + t0) * NQKV + 1024 + hh * 64;
  bf16x8 kv = *(const bf16x8*)&Ck[(size_t)row * NQKV + db8];
  float* kd = kout + ((size_t)bh * 2048 + t0 + row) * 64 + db8;
#pragma unroll
  for (int j = 0; j < 8; ++j) kd[j] = (float)kv[j];
  bf16x8 vv = *(const bf16x8*)&Ck[(size_t)row * NQKV + 1024 + db8];
  const unsigned short* vb = (const unsigned short*)&vv;
  float* vd = vout + ((size_t)bh * 2048 + t0 + row) * 64 + db8;
#pragma unroll
  for (int j = 0; j < 8; ++j) {
    vd[j] = (float)vv[j];
    vt[db8 + j][row] = vb[j];
  }
  __syncthreads();
  int d = tid >> 2, t8 = (tid & 3) * 8;
  union { unsigned short u[8]; bf16x8 v8; } o;
#pragma unroll
  for (int j = 0; j < 8; ++j) o.u[j] = vt[d][t8 + j];
  *(bf16x8*)&vtb[((size_t)bh * 64 + d) * 2048 + t0 + t8] = o.v8;
}

// ---- 128^2 GEMM: dbuf + counted-vmcnt + granule-XOR LDS swizzle, 4 waves, BK=64.
// EPI 5: plain bf16 row-major = acc+bias (QKV).  EPI 2: bf16 = gelu_tanh(acc+bias).
// EPI 3: x2 = acc+bias+res AND seed paux = x2 + bias2 (o-proj).
// EPI 4: atomicAdd(fout, acc) — split-K partials onto seeded output.
template <int EPI, int SK>
__global__ __launch_bounds__(256) void gemm_kernel(
    const bf16* __restrict__ A, const bf16* __restrict__ Bt, const float* __restrict__ bias,
    bf16* __restrict__ bfout, float* __restrict__ fout, const float* __restrict__ res,
    float* __restrict__ paux, const float* __restrict__ bias2, int M, int N, int K) {
  __shared__ bf16 Al[2 * 128 * 64];
  __shared__ bf16 Bl[2 * 128 * 64];
  int tid = threadIdx.x, w = tid >> 6, l = tid & 63;
  int g = l >> 4, c = l & 15;
  int nwg = gridDim.x * gridDim.y;
  int bidl = blockIdx.y * gridDim.x + blockIdx.x;
  int wgid = (bidl & 7) * (nwg >> 3) + (bidl >> 3);
  int bx = wgid % gridDim.x, by = wgid / gridDim.x;
  int m0 = by * 128, n0 = bx * 128;
  int wm = (w >> 1) * 64, wn = (w & 1) * 64;
  int Kc = K / SK;
  int kbase = (SK > 1) ? (int)blockIdx.z * Kc : 0;
  int KT = Kc >> 6;
  int lrow = l >> 3;
  int sgr = (l & 7) ^ lrow;  // pre-swizzled source granule (involution w/ read)

  const bf16* gA = A + (size_t)(m0 + w * 32 + lrow) * K + kbase + sgr * 8;
  const bf16* gB = Bt + (size_t)(n0 + w * 32 + lrow) * K + kbase + sgr * 8;

  auto stage = [&](int kt, int buf) {
#pragma unroll
    for (int i = 0; i < 4; ++i) {
      gload16(gA + (size_t)i * 8 * K + kt * 64, Al + buf * 8192 + (w * 4 + i) * 512);
      gload16(gB + (size_t)i * 8 * K + kt * 64, Bl + buf * 8192 + (w * 4 + i) * 512);
    }
  };
  auto compute = [&](int buf, f32x4 (&acc)[4][4]) {
#pragma unroll
    for (int ch = 0; ch < 2; ++ch) {
      bf16x8 af[4], bfr[4];
#pragma unroll
      for (int f = 0; f < 4; ++f)
        af[f] = *(const bf16x8*)&Al[buf * 8192 + (wm + f * 16 + c) * 64 +
                                    (((ch * 4 + g) ^ (c & 7)) << 3)];
#pragma unroll
      for (int f = 0; f < 4; ++f)
        bfr[f] = *(const bf16x8*)&Bl[buf * 8192 + (wn + f * 16 + c) * 64 +
                                     (((ch * 4 + g) ^ (c & 7)) << 3)];
#pragma unroll
      for (int mf = 0; mf < 4; ++mf)
#pragma unroll
        for (int nf = 0; nf < 4; ++nf) acc[mf][nf] = mfma16(af[mf], bfr[nf], acc[mf][nf]);
    }
  };

  f32x4 acc[4][4] = {};
  stage(0, 0);
  for (int kt = 0; kt < KT; ++kt) {
    int cur = kt & 1;
    if (kt + 1 < KT) {
      stage(kt + 1, cur ^ 1);
      WAIT_VM(8);  // own tile-kt loads landed; next tile's 8 stay in flight
    } else {
      WAIT_VM(0);
    }
    SBAR();
    __builtin_amdgcn_s_setprio(1);
    compute(cur, acc);
    __builtin_amdgcn_s_setprio(0);
    __builtin_amdgcn_sched_barrier(0);
    SBAR();
  }

#pragma unroll
  for (int mf = 0; mf < 4; ++mf) {
#pragma unroll
    for (int nf = 0; nf < 4; ++nf) {
      int gn = n0 + wn + nf * 16 + c;
      float bv = bias ? bias[gn] : 0.f;
#pragma unroll
      for (int r = 0; r < 4; ++r) {
        int gm = m0 + wm + mf * 16 + g * 4 + r;
        float vr = acc[mf][nf][r];
        float v = vr + bv;
        if (EPI == 4) {
          atomicAdd(fout + (size_t)gm * N + gn, vr);
        } else if (EPI == 5) {
          bfout[(size_t)gm * N + gn] = __float2bfloat16(v);
        } else if (EPI == 3) {
          size_t idx = (size_t)gm * N + gn;
          float t = v + res[idx];
          fout[idx] = t;                 // x2
          paux[idx] = t + bias2[gn];     // seed out for MLP2 atomics
        } else {  // EPI == 2
          size_t idx = (size_t)gm * N + gn;
          bfout[idx] = __float2bfloat16(gelu_tanh(v));
        }
      }
    }
  }
}

// ---- Flash attention (causal), KV-split x2, Q/K read from C[4096][3072] (strided),
// V^T from vtb. Swapped QK^T; unnormalized o + m,l partials. Mask -3e38.
__global__ __launch_bounds__(256, 2) void attn_kernel(const bf16* __restrict__ Cq,
                                                      const bf16* __restrict__ Vt,
                                                      bf16* __restrict__ o0p,
                                                      bf16* __restrict__ o1p,
                                                      float* __restrict__ ml) {
  constexpr int LDP = 72;
  __shared__ bf16 Kl[2][64 * 64];
  __shared__ bf16 Vl[2][64 * 64];
  __shared__ bf16 Pl[4][2][16 * LDP];
  __shared__ float alw[4][2][16];
  int tid = threadIdx.x, w = tid >> 6, l = tid & 63, g = l >> 4, c = l & 15;
  int bid = blockIdx.x;
  int bh = bid & 31;
  int rest = bid >> 5;
  int qt = 15 - (rest >> 1);
  int half = rest & 1;
  int qbase = qt * 128 + w * 32;
  int b = bh >> 4, hh = bh & 15;
  const bf16* Qh = Cq + (size_t)(b * 2048) * NQKV + hh * 64;  // [t][d] stride NQKV
  const bf16* Kh = Qh + 1024;
  const bf16* Vh = Vt + (size_t)bh * T_ * D_;                 // [d][t]

  int NT = 2 * qt + 2, H0 = qt + 1;
  int t0 = half ? H0 : 0, t1 = half ? NT : H0;

  int srow = l >> 3;
  int sce = ((l & 7) * 8) ^ (srow << 3);
  int cswz = (c & 7) << 3;

  auto stage = [&](int ti, int buf) {
#pragma unroll
    for (int i = 0; i < 2; ++i) {
      int row = i * 32 + w * 8 + srow;
      gload16(&Kh[(size_t)(ti * 64 + row) * NQKV + sce], &Kl[buf][i * 2048 + w * 512]);
      gload16(&Vh[(size_t)row * T_ + ti * 64 + sce], &Vl[buf][i * 2048 + w * 512]);
    }
  };

  stage(t0, 0);

  bf16x8 aq[2][2];
#pragma unroll
  for (int qf = 0; qf < 2; ++qf)
#pragma unroll
    for (int ch = 0; ch < 2; ++ch)
      aq[qf][ch] =
          *(const bf16x8*)&Qh[(size_t)(qbase + qf * 16 + c) * NQKV + ch * 32 + g * 8];

  f32x4 o[2][4] = {};
  float mrun[2] = {-1e30f, -1e30f};
  float lrun[2] = {0.f, 0.f};

  __syncthreads();

  for (int ti = t0; ti < t1; ++ti) {
    int cur = (ti - t0) & 1;
    int kv0 = ti * 64;
    if (ti + 1 < t1) stage(ti + 1, cur ^ 1);

    f32x4 sf[2][4];
#pragma unroll
    for (int kb = 0; kb < 4; ++kb) {
      bf16x8 bk0 = *(const bf16x8*)&Kl[cur][(kb * 16 + c) * 64 + ((g * 8) ^ cswz)];
      bf16x8 bk1 = *(const bf16x8*)&Kl[cur][(kb * 16 + c) * 64 + ((32 + g * 8) ^ cswz)];
#pragma unroll
      for (int qf = 0; qf < 2; ++qf) {
        f32x4 t = {};
        t = mfma16(bk0, aq[qf][0], t);
        t = mfma16(bk1, aq[qf][1], t);
        sf[qf][kb] = t;
      }
    }

    float s[2][4][4];
#pragma unroll
    for (int qf = 0; qf < 2; ++qf)
#pragma unroll
      for (int kb = 0; kb < 4; ++kb)
#pragma unroll
        for (int r = 0; r < 4; ++r) s[qf][kb][r] = sf[qf][kb][r] * 0.125f;
    if (kv0 + 63 > qbase) {
#pragma unroll
      for (int qf = 0; qf < 2; ++qf)
#pragma unroll
        for (int kb = 0; kb < 4; ++kb)
#pragma unroll
          for (int r = 0; r < 4; ++r) {
            int qi = qbase + qf * 16 + c;
            int kv = kv0 + kb * 16 + g * 4 + r;
            if (kv > qi) s[qf][kb][r] = -3.0e38f;
          }
    }

#pragma unroll
    for (int qf = 0; qf < 2; ++qf) {
      float m01 = fmaxf(fmaxf(s[qf][0][0], s[qf][0][1]), fmaxf(s[qf][0][2], s[qf][0][3]));
      float m23 = fmaxf(fmaxf(s[qf][1][0], s[qf][1][1]), fmaxf(s[qf][1][2], s[qf][1][3]));
      float m45 = fmaxf(fmaxf(s[qf][2][0], s[qf][2][1]), fmaxf(s[qf][2][2], s[qf][2][3]));
      float m67 = fmaxf(fmaxf(s[qf][3][0], s[qf][3][1]), fmaxf(s[qf][3][2], s[qf][3][3]));
      float tm = fmaxf(fmaxf(m01, m23), fmaxf(m45, m67));
      tm = fmaxf(tm, __shfl_xor(tm, 16));
      tm = fmaxf(tm, __shfl_xor(tm, 32));
      float mn = fmaxf(mrun[qf], tm);
      float al = __expf(mrun[qf] - mn);
      mrun[qf] = mn;
      float asum = 0.f;
#pragma unroll
      for (int kb = 0; kb < 4; ++kb)
#pragma unroll
        for (int r = 0; r < 4; ++r) {
          float pv = __expf(s[qf][kb][r] - mn);
          s[qf][kb][r] = pv;
          asum += pv;
        }
      asum += __shfl_xor(asum, 16);
      asum += __shfl_xor(asum, 32);
      lrun[qf] = lrun[qf] * al + asum;
      if (l < 16) alw[w][qf][c] = al;
    }

#pragma unroll
    for (int qf = 0; qf < 2; ++qf)
#pragma unroll
      for (int kb = 0; kb < 4; ++kb) {
        union { unsigned short u[4]; uint2 v2; } pk;
#pragma unroll
        for (int r = 0; r < 4; ++r) pk.u[r] = bfbits(s[qf][kb][r]);
        *(uint2*)&Pl[w][qf][c * LDP + kb * 16 + g * 4] = pk.v2;
      }

#pragma unroll
    for (int qf = 0; qf < 2; ++qf) {
      f32x4 a4 = *(const f32x4*)&alw[w][qf][g * 4];
#pragma unroll
      for (int db = 0; db < 4; ++db)
#pragma unroll
        for (int r = 0; r < 4; ++r) o[qf][db][r] *= a4[r];
    }

    bf16x8 bvv[4][2];
#pragma unroll
    for (int db = 0; db < 4; ++db)
#pragma unroll
      for (int ck = 0; ck < 2; ++ck)
        bvv[db][ck] = *(const bf16x8*)&Vl[cur][(db * 16 + c) * 64 + ((ck * 32 + g * 8) ^ cswz)];

#pragma unroll
    for (int qf = 0; qf < 2; ++qf) {
      bf16x8 pa0 = *(const bf16x8*)&Pl[w][qf][c * LDP + g * 8];
      bf16x8 pa1 = *(const bf16x8*)&Pl[w][qf][c * LDP + 32 + g * 8];
#pragma unroll
      for (int db = 0; db < 4; ++db) {
        o[qf][db] = mfma16(pa0, bvv[db][0], o[qf][db]);
        o[qf][db] = mfma16(pa1, bvv[db][1], o[qf][db]);
      }
    }
    __syncthreads();
  }

  bf16* op = half ? o1p : o0p;
  int rowbase = bh * 2048 + qt * 128 + w * 32;
#pragma unroll
  for (int qf = 0; qf < 2; ++qf)
#pragma unroll
    for (int r = 0; r < 4; ++r)
#pragma unroll
      for (int db = 0; db < 4; ++db)
        op[(size_t)(rowbase + qf * 16 + g * 4 + r) * 64 + db * 16 + c] =
            __float2bfloat16(o[qf][db][r]);
  if (l < 16) {
    float* mh = ml + half * 131072;
#pragma unroll
    for (int qf = 0; qf < 2; ++qf) {
      mh[rowbase + qf * 16 + c] = mrun[qf];
      mh[65536 + rowbase + qf * 16 + c] = lrun[qf];
    }
  }
}

// ---- merge the two KV-halves ----
__global__ __launch_bounds__(256) void merge_attn(const bf16* __restrict__ o0,
                                                  const bf16* __restrict__ o1,
                                                  const float* __restrict__ ml,
                                                  bf16* __restrict__ ctx) {
  int idx = blockIdx.x * 256 + threadIdx.x;
  int row = idx >> 2, dc = (idx & 3) * 16;
  float m0 = ml[row], l0 = ml[65536 + row];
  float m1 = ml[131072 + row], l1 = ml[196608 + row];
  float Mx = fmaxf(m0, m1);
  float s0 = __expf(m0 - Mx), s1 = __expf(m1 - Mx);
  float inv = 1.0f / (l0 * s0 + l1 * s1);
  const bf16x8* p0 = (const bf16x8*)&o0[(size_t)row * 64 + dc];
  const bf16x8* p1 = (const bf16x8*)&o1[(size_t)row * 64 + dc];
  bf16x8 a0 = p0[0], a1 = p0[1], b0 = p1[0], b1 = p1[1];
  int bh = row >> 11, t = row & 2047;
  int b_ = bh >> 4, hh = bh & 15;
  bf16* dst = ctx + ((size_t)(b_ * T_ + t)) * C_ + hh * D_ + dc;
#pragma unroll
  for (int j = 0; j < 8; ++j) {
    dst[j] = __float2bfloat16(((float)a0[j] * s0 + (float)b0[j] * s1) * inv);
    dst[8 + j] = __float2bfloat16(((float)a1[j] * s0 + (float)b1[j] * s1) * inv);
  }
}

extern "C" void kernel_launch(void* const* d_in, const int* in_sizes, int n_in, void* d_out,
                              int out_size, void* d_ws, size_t ws_size, hipStream_t stream) {
  const float* x = (const float*)d_in[0];
  const float* anw = (const float*)d_in[2];
  const float* mnw = (const float*)d_in[3];
  const float* q_w = (const float*)d_in[4];
  const float* q_b = (const float*)d_in[5];
  const float* k_w = (const float*)d_in[6];
  const float* k_b = (const float*)d_in[7];
  const float* v_w = (const float*)d_in[8];
  const float* v_b = (const float*)d_in[9];
  const float* o_w = (const float*)d_in[10];
  const float* o_b = (const float*)d_in[11];
  const float* w1 = (const float*)d_in[12];
  const float* b1 = (const float*)d_in[13];
  const float* w2 = (const float*)d_in[14];
  const float* b2 = (const float*)d_in[15];
  float* out = (float*)d_out;
  char* ws = (char*)d_ws;

  // ws map (80 MB), MB offsets:
  bf16* owT = (bf16*)(ws + 0);                    // 0-2
  bf16* w1T = (bf16*)(ws + 2097152);              // 2-10
  bf16* w2T = (bf16*)(ws + 10485760);             // 10-18
  bf16* h = (bf16*)(ws + 18874368);               // 18-26 (also m)
  bf16* qkvT = (bf16*)(ws + 27262976);            // 26-32; dead after QKV
  bf16* Cq = (bf16*)(ws + 33554432);              // 32-56 [4096][3072]; dead after attn
  bf16* vtb = (bf16*)(ws + 58720256);             // 56-64; dead after attn
  bf16* o0p = (bf16*)(ws + 67108864);             // 64-72; dead after merge
  bf16* o1p = (bf16*)(ws + 75497472);             // 72-80; dead after merge
  float* ml = (float*)(ws + 27262976);            // 26-27 over qkvT (dead after QKV)
  float* qkvb = (float*)(ws + 67108864);          // over o0p (dead before attn)
  bf16* ctx = (bf16*)(ws + 33554432);             // 32-40 over Cq head (after attn)
  float* x2 = (float*)(ws + 41943040);            // 40-56 over Cq tail
  bf16* m = h;
  bf16* hid = (bf16*)(ws + 50331648);             // 48-80 (x2 dead after rms2)

  // one dispatch: all weight transposes + bias pack
  prep_all<<<12300, 256, 0, stream>>>(q_w, k_w, v_w, o_w, w1, w2, q_b, k_b, v_b,
                                      qkvT, owT, w1T, w2T, qkvb);

  rmsnorm_kernel<<<4096, 256, 0, stream>>>(x, anw, h);

  // fused QKV -> plain row-major bf16 C[4096][3072]
  gemm_kernel<5, 1><<<dim3(24, 32), 256, 0, stream>>>(
      h, qkvT, qkvb, Cq, nullptr, nullptr, nullptr, nullptr, 4096, 3072, 1024);

  // k/v f32 outputs + V^T (all coalesced)
  qkv_post<<<dim3(64, 32), 256, 0, stream>>>(Cq, vtb, out + 4194304, out + 8388608);

  // attention, KV-split x2 + merge
  attn_kernel<<<1024, 256, 0, stream>>>(Cq, vtb, o0p, o1p, ml);
  merge_attn<<<1024, 256, 0, stream>>>(o0p, o1p, ml, ctx);

  // o-proj: x2 = ctx@o_w + o_b + x; seed out = x2 + b2
  gemm_kernel<3, 1><<<dim3(8, 32), 256, 0, stream>>>(
      ctx, owT, o_b, nullptr, x2, x, out, b2, 4096, 1024, 1024);

  rmsnorm_kernel<<<4096, 256, 0, stream>>>(x2, mnw, m);

  // MLP1 (tanh gelu)
  gemm_kernel<2, 1><<<dim3(32, 32), 256, 0, stream>>>(
      m, w1T, b1, hid, nullptr, nullptr, nullptr, nullptr, 4096, 4096, 1024);
  // MLP2 split-K=2, atomic onto seeded out
  gemm_kernel<4, 2><<<dim3(8, 32, 2), 256, 0, stream>>>(
      hid, w2T, nullptr, nullptr, out, nullptr, nullptr, nullptr, 4096, 1024, 4096);
}

// Round 21
// 260.992 us; speedup vs baseline: 1.0921x; 1.0049x over previous
//
#include <hip/hip_runtime.h>
#include <hip/hip_bf16.h>

// Transformer block fwd (B=2,T=2048,C=1024,H=16,D=64,HID=4096), bf16 MFMA compute.
// Round 21 (= R18 best-config + rmsnorm1 fused into prep_all): fused prep dispatch
// (6 transposes + bias pack + first RMSNorm); 128^2 GEMMs with dbuf + counted-vmcnt
// + granule-XOR swizzle; QKV -> row-major C + qkv_post; KV-split x2 flash attention
// + merge; tanh GELU; MLP2 atomic split-K=2.

#define B_ 2
#define T_ 2048
#define C_ 1024
#define H_ 16
#define D_ 64
#define HID_ 4096
#define M_ 4096  // B*T
#define NQKV 3072

typedef __bf16 bf16x8 __attribute__((ext_vector_type(8)));
typedef float f32x4 __attribute__((ext_vector_type(4)));
using bf16 = __hip_bfloat16;

#define WAIT_VM(N) asm volatile("s_waitcnt vmcnt(" #N ")" ::: "memory")
#define SBAR() asm volatile("s_barrier" ::: "memory")

static __device__ __forceinline__ f32x4 mfma16(bf16x8 a, bf16x8 b, f32x4 c) {
  return __builtin_amdgcn_mfma_f32_16x16x32_bf16(a, b, c, 0, 0, 0);
}

static __device__ __forceinline__ void gload16(const bf16* g, bf16* l) {
  __builtin_amdgcn_global_load_lds(
      (const __attribute__((address_space(1))) unsigned int*)g,
      (__attribute__((address_space(3))) unsigned int*)l, 16, 0, 0);
}

static __device__ __forceinline__ unsigned short bfbits(float x) {
  __hip_bfloat16 h = __float2bfloat16(x);
  return *(unsigned short*)&h;
}

// overflow-safe tanh-form GELU (|err| vs erf-GELU ~3e-3 << 0.119 tolerance)
static __device__ __forceinline__ float gelu_tanh(float v) {
  float z = 0.7978845608f * (v + 0.044715f * v * v * v);
  float az = fabsf(z);
  float e = __expf(-2.0f * az);
  float th = (1.0f - e) / (1.0f + e);
  th = copysignf(th, z);
  return 0.5f * v * (1.0f + th);
}

// ---- prep_all: one dispatch: 6 weight transposes (f32 [K][N] -> bf16 [N][K]) +
// qkv bias pack + first RMSNorm (x,anw -> h). Block map: [0,4096) q/k/v/o 32x32
// tiles; [4096,8192) w1; [8192,12288) w2; [12288,12300) bias; [12300,16396) rmsnorm.
__global__ __launch_bounds__(256) void prep_all(
    const float* __restrict__ q_w, const float* __restrict__ k_w,
    const float* __restrict__ v_w, const float* __restrict__ o_w,
    const float* __restrict__ w1, const float* __restrict__ w2,
    const float* __restrict__ q_b, const float* __restrict__ k_b,
    const float* __restrict__ v_b, const float* __restrict__ x,
    const float* __restrict__ anw, bf16* __restrict__ qkvT, bf16* __restrict__ owT,
    bf16* __restrict__ w1T, bf16* __restrict__ w2T, float* __restrict__ qkvb,
    bf16* __restrict__ h) {
  int bid = blockIdx.x, tid = threadIdx.x;
  if (bid >= 12300) {
    // RMSNorm row
    int row = bid - 12300;
    float4 v = ((const float4*)(x + (size_t)row * C_))[tid];
    float ss = v.x * v.x + v.y * v.y + v.z * v.z + v.w * v.w;
#pragma unroll
    for (int d = 1; d < 64; d <<= 1) ss += __shfl_xor(ss, d);
    __shared__ float wsum[4];
    if ((tid & 63) == 0) wsum[tid >> 6] = ss;
    __syncthreads();
    float tot = wsum[0] + wsum[1] + wsum[2] + wsum[3];
    float r = rsqrtf(tot * (1.0f / C_) + 1e-5f);
    float4 wv = ((const float4*)anw)[tid];
    bf16* o = h + (size_t)row * C_ + tid * 4;
    o[0] = __float2bfloat16(v.x * wv.x * r);
    o[1] = __float2bfloat16(v.y * wv.y * r);
    o[2] = __float2bfloat16(v.z * wv.z * r);
    o[3] = __float2bfloat16(v.w * wv.w * r);
    return;
  }
  if (bid >= 12288) {
    int i = (bid - 12288) * 256 + tid;
    qkvb[i] = i < 1024 ? q_b[i] : (i < 2048 ? k_b[i - 1024] : v_b[i - 2048]);
    return;
  }
  const float* in;
  bf16* out;
  int K, N, tile;
  if (bid < 4096) {
    int which = bid >> 10;
    tile = bid & 1023;
    K = 1024; N = 1024;
    if (which == 0) { in = q_w; out = qkvT; }
    else if (which == 1) { in = k_w; out = qkvT + 1048576; }
    else if (which == 2) { in = v_w; out = qkvT + 2097152; }
    else { in = o_w; out = owT; }
  } else if (bid < 8192) {
    tile = bid - 4096; K = 1024; N = 4096; in = w1; out = w1T;
  } else {
    tile = bid - 8192; K = 4096; N = 1024; in = w2; out = w2T;
  }
  int ntx = N >> 5;
  int n0 = (tile % ntx) * 32, k0 = (tile / ntx) * 32;
  __shared__ float t32[32][33];
  int tx = tid & 31, ty = tid >> 5;
#pragma unroll
  for (int i = 0; i < 4; ++i) {
    int r = ty + i * 8;
    t32[r][tx] = in[(size_t)(k0 + r) * N + n0 + tx];
  }
  __syncthreads();
#pragma unroll
  for (int i = 0; i < 4; ++i) {
    int r = ty + i * 8;
    out[(size_t)(n0 + r) * K + k0 + tx] = __float2bfloat16(t32[tx][r]);
  }
}

// ---- RMSNorm: x f32 [rows][1024] -> out bf16 (used for the second norm) ----
__global__ __launch_bounds__(256) void rmsnorm_kernel(const float* __restrict__ x,
                                                      const float* __restrict__ w,
                                                      bf16* __restrict__ out) {
  int row = blockIdx.x, tid = threadIdx.x;
  float4 v = ((const float4*)(x + (size_t)row * C_))[tid];
  float ss = v.x * v.x + v.y * v.y + v.z * v.z + v.w * v.w;
#pragma unroll
  for (int d = 1; d < 64; d <<= 1) ss += __shfl_xor(ss, d);
  __shared__ float wsum[4];
  if ((tid & 63) == 0) wsum[tid >> 6] = ss;
  __syncthreads();
  float tot = wsum[0] + wsum[1] + wsum[2] + wsum[3];
  float r = rsqrtf(tot * (1.0f / C_) + 1e-5f);
  float4 wv = ((const float4*)w)[tid];
  bf16* o = out + (size_t)row * C_ + tid * 4;
  o[0] = __float2bfloat16(v.x * wv.x * r);
  o[1] = __float2bfloat16(v.y * wv.y * r);
  o[2] = __float2bfloat16(v.z * wv.z * r);
  o[3] = __float2bfloat16(v.w * wv.w * r);
}

// ---- qkv_post: from C[4096][3072] bf16 produce kout/vout f32 (B,H,T,D) and
// vtb bf16 V^T (B,H,D,T). All reads/writes coalesced; V^T via LDS tile (ushort bits).
__global__ __launch_bounds__(256) void qkv_post(const bf16* __restrict__ Cq,
                                                bf16* __restrict__ vtb,
                                                float* __restrict__ kout,
                                                float* __restrict__ vout) {
  __shared__ unsigned short vt[64][33];
  int tid = threadIdx.x, bh = blockIdx.y, t0 = blockIdx.x * 32;
  int b = bh >> 4, hh = bh & 15;
  int row = tid >> 3, db8 = (tid & 7) * 8;
  const bf16* Ck = Cq + (size_t)(b * 2048 + t0) * NQKV + 1024 + hh * 64;
  bf16x8 kv = *(const bf16x8*)&Ck[(size_t)row * NQKV + db8];
  float* kd = kout + ((size_t)bh * 2048 + t0 + row) * 64 + db8;
#pragma unroll
  for (int j = 0; j < 8; ++j) kd[j] = (float)kv[j];
  bf16x8 vv = *(const bf16x8*)&Ck[(size_t)row * NQKV + 1024 + db8];
  const unsigned short* vb = (const unsigned short*)&vv;
  float* vd = vout + ((size_t)bh * 2048 + t0 + row) * 64 + db8;
#pragma unroll
  for (int j = 0; j < 8; ++j) {
    vd[j] = (float)vv[j];
    vt[db8 + j][row] = vb[j];
  }
  __syncthreads();
  int d = tid >> 2, t8 = (tid & 3) * 8;
  union { unsigned short u[8]; bf16x8 v8; } o;
#pragma unroll
  for (int j = 0; j < 8; ++j) o.u[j] = vt[d][t8 + j];
  *(bf16x8*)&vtb[((size_t)bh * 64 + d) * 2048 + t0 + t8] = o.v8;
}

// ---- 128^2 GEMM: dbuf + counted-vmcnt + granule-XOR LDS swizzle, 4 waves, BK=64.
// EPI 5: plain bf16 row-major = acc+bias (QKV).  EPI 2: bf16 = gelu_tanh(acc+bias).
// EPI 3: x2 = acc+bias+res AND seed paux = x2 + bias2 (o-proj).
// EPI 4: atomicAdd(fout, acc) — split-K partials onto seeded output.
template <int EPI, int SK>
__global__ __launch_bounds__(256) void gemm_kernel(
    const bf16* __restrict__ A, const bf16* __restrict__ Bt, const float* __restrict__ bias,
    bf16* __restrict__ bfout, float* __restrict__ fout, const float* __restrict__ res,
    float* __restrict__ paux, const float* __restrict__ bias2, int M, int N, int K) {
  __shared__ bf16 Al[2 * 128 * 64];
  __shared__ bf16 Bl[2 * 128 * 64];
  int tid = threadIdx.x, w = tid >> 6, l = tid & 63;
  int g = l >> 4, c = l & 15;
  int nwg = gridDim.x * gridDim.y;
  int bidl = blockIdx.y * gridDim.x + blockIdx.x;
  int wgid = (bidl & 7) * (nwg >> 3) + (bidl >> 3);
  int bx = wgid % gridDim.x, by = wgid / gridDim.x;
  int m0 = by * 128, n0 = bx * 128;
  int wm = (w >> 1) * 64, wn = (w & 1) * 64;
  int Kc = K / SK;
  int kbase = (SK > 1) ? (int)blockIdx.z * Kc : 0;
  int KT = Kc >> 6;
  int lrow = l >> 3;
  int sgr = (l & 7) ^ lrow;  // pre-swizzled source granule (involution w/ read)

  const bf16* gA = A + (size_t)(m0 + w * 32 + lrow) * K + kbase + sgr * 8;
  const bf16* gB = Bt + (size_t)(n0 + w * 32 + lrow) * K + kbase + sgr * 8;

  auto stage = [&](int kt, int buf) {
#pragma unroll
    for (int i = 0; i < 4; ++i) {
      gload16(gA + (size_t)i * 8 * K + kt * 64, Al + buf * 8192 + (w * 4 + i) * 512);
      gload16(gB + (size_t)i * 8 * K + kt * 64, Bl + buf * 8192 + (w * 4 + i) * 512);
    }
  };
  auto compute = [&](int buf, f32x4 (&acc)[4][4]) {
#pragma unroll
    for (int ch = 0; ch < 2; ++ch) {
      bf16x8 af[4], bfr[4];
#pragma unroll
      for (int f = 0; f < 4; ++f)
        af[f] = *(const bf16x8*)&Al[buf * 8192 + (wm + f * 16 + c) * 64 +
                                    (((ch * 4 + g) ^ (c & 7)) << 3)];
#pragma unroll
      for (int f = 0; f < 4; ++f)
        bfr[f] = *(const bf16x8*)&Bl[buf * 8192 + (wn + f * 16 + c) * 64 +
                                     (((ch * 4 + g) ^ (c & 7)) << 3)];
#pragma unroll
      for (int mf = 0; mf < 4; ++mf)
#pragma unroll
        for (int nf = 0; nf < 4; ++nf) acc[mf][nf] = mfma16(af[mf], bfr[nf], acc[mf][nf]);
    }
  };

  f32x4 acc[4][4] = {};
  stage(0, 0);
  for (int kt = 0; kt < KT; ++kt) {
    int cur = kt & 1;
    if (kt + 1 < KT) {
      stage(kt + 1, cur ^ 1);
      WAIT_VM(8);  // own tile-kt loads landed; next tile's 8 stay in flight
    } else {
      WAIT_VM(0);
    }
    SBAR();
    __builtin_amdgcn_s_setprio(1);
    compute(cur, acc);
    __builtin_amdgcn_s_setprio(0);
    __builtin_amdgcn_sched_barrier(0);
    SBAR();
  }

#pragma unroll
  for (int mf = 0; mf < 4; ++mf) {
#pragma unroll
    for (int nf = 0; nf < 4; ++nf) {
      int gn = n0 + wn + nf * 16 + c;
      float bv = bias ? bias[gn] : 0.f;
#pragma unroll
      for (int r = 0; r < 4; ++r) {
        int gm = m0 + wm + mf * 16 + g * 4 + r;
        float vr = acc[mf][nf][r];
        float v = vr + bv;
        if (EPI == 4) {
          atomicAdd(fout + (size_t)gm * N + gn, vr);
        } else if (EPI == 5) {
          bfout[(size_t)gm * N + gn] = __float2bfloat16(v);
        } else if (EPI == 3) {
          size_t idx = (size_t)gm * N + gn;
          float t = v + res[idx];
          fout[idx] = t;                 // x2
          paux[idx] = t + bias2[gn];     // seed out for MLP2 atomics
        } else {  // EPI == 2
          size_t idx = (size_t)gm * N + gn;
          bfout[idx] = __float2bfloat16(gelu_tanh(v));
        }
      }
    }
  }
}

// ---- Flash attention (causal), KV-split x2, Q/K read from C[4096][3072] (strided),
// V^T from vtb. Swapped QK^T; unnormalized o + m,l partials. Mask -3e38.
__global__ __launch_bounds__(256, 2) void attn_kernel(const bf16* __restrict__ Cq,
                                                      const bf16* __restrict__ Vt,
                                                      bf16* __restrict__ o0p,
                                                      bf16* __restrict__ o1p,
                                                      float* __restrict__ ml) {
  constexpr int LDP = 72;
  __shared__ bf16 Kl[2][64 * 64];
  __shared__ bf16 Vl[2][64 * 64];
  __shared__ bf16 Pl[4][2][16 * LDP];
  __shared__ float alw[4][2][16];
  int tid = threadIdx.x, w = tid >> 6, l = tid & 63, g = l >> 4, c = l & 15;
  int bid = blockIdx.x;
  int bh = bid & 31;
  int rest = bid >> 5;
  int qt = 15 - (rest >> 1);
  int half = rest & 1;
  int qbase = qt * 128 + w * 32;
  int b = bh >> 4, hh = bh & 15;
  const bf16* Qh = Cq + (size_t)(b * 2048) * NQKV + hh * 64;  // [t][d] stride NQKV
  const bf16* Kh = Qh + 1024;
  const bf16* Vh = Vt + (size_t)bh * T_ * D_;                 // [d][t]

  int NT = 2 * qt + 2, H0 = qt + 1;
  int t0 = half ? H0 : 0, t1 = half ? NT : H0;

  int srow = l >> 3;
  int sce = ((l & 7) * 8) ^ (srow << 3);
  int cswz = (c & 7) << 3;

  auto stage = [&](int ti, int buf) {
#pragma unroll
    for (int i = 0; i < 2; ++i) {
      int row = i * 32 + w * 8 + srow;
      gload16(&Kh[(size_t)(ti * 64 + row) * NQKV + sce], &Kl[buf][i * 2048 + w * 512]);
      gload16(&Vh[(size_t)row * T_ + ti * 64 + sce], &Vl[buf][i * 2048 + w * 512]);
    }
  };

  stage(t0, 0);

  bf16x8 aq[2][2];
#pragma unroll
  for (int qf = 0; qf < 2; ++qf)
#pragma unroll
    for (int ch = 0; ch < 2; ++ch)
      aq[qf][ch] =
          *(const bf16x8*)&Qh[(size_t)(qbase + qf * 16 + c) * NQKV + ch * 32 + g * 8];

  f32x4 o[2][4] = {};
  float mrun[2] = {-1e30f, -1e30f};
  float lrun[2] = {0.f, 0.f};

  __syncthreads();

  for (int ti = t0; ti < t1; ++ti) {
    int cur = (ti - t0) & 1;
    int kv0 = ti * 64;
    if (ti + 1 < t1) stage(ti + 1, cur ^ 1);

    f32x4 sf[2][4];
#pragma unroll
    for (int kb = 0; kb < 4; ++kb) {
      bf16x8 bk0 = *(const bf16x8*)&Kl[cur][(kb * 16 + c) * 64 + ((g * 8) ^ cswz)];
      bf16x8 bk1 = *(const bf16x8*)&Kl[cur][(kb * 16 + c) * 64 + ((32 + g * 8) ^ cswz)];
#pragma unroll
      for (int qf = 0; qf < 2; ++qf) {
        f32x4 t = {};
        t = mfma16(bk0, aq[qf][0], t);
        t = mfma16(bk1, aq[qf][1], t);
        sf[qf][kb] = t;
      }
    }

    float s[2][4][4];
#pragma unroll
    for (int qf = 0; qf < 2; ++qf)
#pragma unroll
      for (int kb = 0; kb < 4; ++kb)
#pragma unroll
        for (int r = 0; r < 4; ++r) s[qf][kb][r] = sf[qf][kb][r] * 0.125f;
    if (kv0 + 63 > qbase) {
#pragma unroll
      for (int qf = 0; qf < 2; ++qf)
#pragma unroll
        for (int kb = 0; kb < 4; ++kb)
#pragma unroll
          for (int r = 0; r < 4; ++r) {
            int qi = qbase + qf * 16 + c;
            int kv = kv0 + kb * 16 + g * 4 + r;
            if (kv > qi) s[qf][kb][r] = -3.0e38f;
          }
    }

#pragma unroll
    for (int qf = 0; qf < 2; ++qf) {
      float m01 = fmaxf(fmaxf(s[qf][0][0], s[qf][0][1]), fmaxf(s[qf][0][2], s[qf][0][3]));
      float m23 = fmaxf(fmaxf(s[qf][1][0], s[qf][1][1]), fmaxf(s[qf][1][2], s[qf][1][3]));
      float m45 = fmaxf(fmaxf(s[qf][2][0], s[qf][2][1]), fmaxf(s[qf][2][2], s[qf][2][3]));
      float m67 = fmaxf(fmaxf(s[qf][3][0], s[qf][3][1]), fmaxf(s[qf][3][2], s[qf][3][3]));
      float tm = fmaxf(fmaxf(m01, m23), fmaxf(m45, m67));
      tm = fmaxf(tm, __shfl_xor(tm, 16));
      tm = fmaxf(tm, __shfl_xor(tm, 32));
      float mn = fmaxf(mrun[qf], tm);
      float al = __expf(mrun[qf] - mn);
      mrun[qf] = mn;
      float asum = 0.f;
#pragma unroll
      for (int kb = 0; kb < 4; ++kb)
#pragma unroll
        for (int r = 0; r < 4; ++r) {
          float pv = __expf(s[qf][kb][r] - mn);
          s[qf][kb][r] = pv;
          asum += pv;
        }
      asum += __shfl_xor(asum, 16);
      asum += __shfl_xor(asum, 32);
      lrun[qf] = lrun[qf] * al + asum;
      if (l < 16) alw[w][qf][c] = al;
    }

#pragma unroll
    for (int qf = 0; qf < 2; ++qf)
#pragma unroll
      for (int kb = 0; kb < 4; ++kb) {
        union { unsigned short u[4]; uint2 v2; } pk;
#pragma unroll
        for (int r = 0; r < 4; ++r) pk.u[r] = bfbits(s[qf][kb][r]);
        *(uint2*)&Pl[w][qf][c * LDP + kb * 16 + g * 4] = pk.v2;
      }

#pragma unroll
    for (int qf = 0; qf < 2; ++qf) {
      f32x4 a4 = *(const f32x4*)&alw[w][qf][g * 4];
#pragma unroll
      for (int db = 0; db < 4; ++db)
#pragma unroll
        for (int r = 0; r < 4; ++r) o[qf][db][r] *= a4[r];
    }

    bf16x8 bvv[4][2];
#pragma unroll
    for (int db = 0; db < 4; ++db)
#pragma unroll
      for (int ck = 0; ck < 2; ++ck)
        bvv[db][ck] = *(const bf16x8*)&Vl[cur][(db * 16 + c) * 64 + ((ck * 32 + g * 8) ^ cswz)];

#pragma unroll
    for (int qf = 0; qf < 2; ++qf) {
      bf16x8 pa0 = *(const bf16x8*)&Pl[w][qf][c * LDP + g * 8];
      bf16x8 pa1 = *(const bf16x8*)&Pl[w][qf][c * LDP + 32 + g * 8];
#pragma unroll
      for (int db = 0; db < 4; ++db) {
        o[qf][db] = mfma16(pa0, bvv[db][0], o[qf][db]);
        o[qf][db] = mfma16(pa1, bvv[db][1], o[qf][db]);
      }
    }
    __syncthreads();
  }

  bf16* op = half ? o1p : o0p;
  int rowbase = bh * 2048 + qt * 128 + w * 32;
#pragma unroll
  for (int qf = 0; qf < 2; ++qf)
#pragma unroll
    for (int r = 0; r < 4; ++r)
#pragma unroll
      for (int db = 0; db < 4; ++db)
        op[(size_t)(rowbase + qf * 16 + g * 4 + r) * 64 + db * 16 + c] =
            __float2bfloat16(o[qf][db][r]);
  if (l < 16) {
    float* mh = ml + half * 131072;
#pragma unroll
    for (int qf = 0; qf < 2; ++qf) {
      mh[rowbase + qf * 16 + c] = mrun[qf];
      mh[65536 + rowbase + qf * 16 + c] = lrun[qf];
    }
  }
}

// ---- merge the two KV-halves ----
__global__ __launch_bounds__(256) void merge_attn(const bf16* __restrict__ o0,
                                                  const bf16* __restrict__ o1,
                                                  const float* __restrict__ ml,
                                                  bf16* __restrict__ ctx) {
  int idx = blockIdx.x * 256 + threadIdx.x;
  int row = idx >> 2, dc = (idx & 3) * 16;
  float m0 = ml[row], l0 = ml[65536 + row];
  float m1 = ml[131072 + row], l1 = ml[196608 + row];
  float Mx = fmaxf(m0, m1);
  float s0 = __expf(m0 - Mx), s1 = __expf(m1 - Mx);
  float inv = 1.0f / (l0 * s0 + l1 * s1);
  const bf16x8* p0 = (const bf16x8*)&o0[(size_t)row * 64 + dc];
  const bf16x8* p1 = (const bf16x8*)&o1[(size_t)row * 64 + dc];
  bf16x8 a0 = p0[0], a1 = p0[1], b0 = p1[0], b1 = p1[1];
  int bh = row >> 11, t = row & 2047;
  int b_ = bh >> 4, hh = bh & 15;
  bf16* dst = ctx + ((size_t)(b_ * T_ + t)) * C_ + hh * D_ + dc;
#pragma unroll
  for (int j = 0; j < 8; ++j) {
    dst[j] = __float2bfloat16(((float)a0[j] * s0 + (float)b0[j] * s1) * inv);
    dst[8 + j] = __float2bfloat16(((float)a1[j] * s0 + (float)b1[j] * s1) * inv);
  }
}

extern "C" void kernel_launch(void* const* d_in, const int* in_sizes, int n_in, void* d_out,
                              int out_size, void* d_ws, size_t ws_size, hipStream_t stream) {
  const float* x = (const float*)d_in[0];
  const float* anw = (const float*)d_in[2];
  const float* mnw = (const float*)d_in[3];
  const float* q_w = (const float*)d_in[4];
  const float* q_b = (const float*)d_in[5];
  const float* k_w = (const float*)d_in[6];
  const float* k_b = (const float*)d_in[7];
  const float* v_w = (const float*)d_in[8];
  const float* v_b = (const float*)d_in[9];
  const float* o_w = (const float*)d_in[10];
  const float* o_b = (const float*)d_in[11];
  const float* w1 = (const float*)d_in[12];
  const float* b1 = (const float*)d_in[13];
  const float* w2 = (const float*)d_in[14];
  const float* b2 = (const float*)d_in[15];
  float* out = (float*)d_out;
  char* ws = (char*)d_ws;

  // ws map (80 MB), MB offsets:
  bf16* owT = (bf16*)(ws + 0);                    // 0-2
  bf16* w1T = (bf16*)(ws + 2097152);              // 2-10
  bf16* w2T = (bf16*)(ws + 10485760);             // 10-18
  bf16* h = (bf16*)(ws + 18874368);               // 18-26 (also m)
  bf16* qkvT = (bf16*)(ws + 27262976);            // 26-32; dead after QKV
  bf16* Cq = (bf16*)(ws + 33554432);              // 32-56 [4096][3072]; dead after attn
  bf16* vtb = (bf16*)(ws + 58720256);             // 56-64; dead after attn
  bf16* o0p = (bf16*)(ws + 67108864);             // 64-72; dead after merge
  bf16* o1p = (bf16*)(ws + 75497472);             // 72-80; dead after merge
  float* ml = (float*)(ws + 27262976);            // 26-27 over qkvT (dead after QKV)
  float* qkvb = (float*)(ws + 67108864);          // over o0p (dead before attn)
  bf16* ctx = (bf16*)(ws + 33554432);             // 32-40 over Cq head (after attn)
  float* x2 = (float*)(ws + 41943040);            // 40-56 over Cq tail
  bf16* m = h;
  bf16* hid = (bf16*)(ws + 50331648);             // 48-80 (x2 dead after rms2)

  // one dispatch: all weight transposes + bias pack + first RMSNorm
  prep_all<<<16396, 256, 0, stream>>>(q_w, k_w, v_w, o_w, w1, w2, q_b, k_b, v_b,
                                      x, anw, qkvT, owT, w1T, w2T, qkvb, h);

  // fused QKV -> plain row-major bf16 C[4096][3072]
  gemm_kernel<5, 1><<<dim3(24, 32), 256, 0, stream>>>(
      h, qkvT, qkvb, Cq, nullptr, nullptr, nullptr, nullptr, 4096, 3072, 1024);

  // k/v f32 outputs + V^T (all coalesced)
  qkv_post<<<dim3(64, 32), 256, 0, stream>>>(Cq, vtb, out + 4194304, out + 8388608);

  // attention, KV-split x2 + merge
  attn_kernel<<<1024, 256, 0, stream>>>(Cq, vtb, o0p, o1p, ml);
  merge_attn<<<1024, 256, 0, stream>>>(o0p, o1p, ml, ctx);

  // o-proj: x2 = ctx@o_w + o_b + x; seed out = x2 + b2
  gemm_kernel<3, 1><<<dim3(8, 32), 256, 0, stream>>>(
      ctx, owT, o_b, nullptr, x2, x, out, b2, 4096, 1024, 1024);

  rmsnorm_kernel<<<4096, 256, 0, stream>>>(x2, mnw, m);

  // MLP1 (tanh gelu)
  gemm_kernel<2, 1><<<dim3(32, 32), 256, 0, stream>>>(
      m, w1T, b1, hid, nullptr, nullptr, nullptr, nullptr, 4096, 4096, 1024);
  // MLP2 split-K=2, atomic onto seeded out
  gemm_kernel<4, 2><<<dim3(8, 32, 2), 256, 0, stream>>>(
      hid, w2T, nullptr, nullptr, out, nullptr, nullptr, nullptr, 4096, 1024, 4096);
}